// Round 1
// 649.738 us; speedup vs baseline: 1.0277x; 1.0277x over previous
//
#include <hip/hip_runtime.h>
#include <hip/hip_bf16.h>

#define HDIM 128
#define NSTAGE 7
#define CHUNK_LOG 13
#define CHUNK (1 << CHUNK_LOG)

typedef __bf16 bf16x8 __attribute__((ext_vector_type(8)));
typedef __bf16 bf16x4 __attribute__((ext_vector_type(4)));
typedef float floatx16 __attribute__((ext_vector_type(16)));
typedef float floatx4 __attribute__((ext_vector_type(4)));

__device__ __forceinline__ float silu_f(float x) {
    return x * __builtin_amdgcn_rcpf(1.0f + __expf(-x));
}

// Weights -> bf16, stage order W1[0],W2[0],W1[1],W2[1],W1[2],W2[2],Wlin.
// XOR swizzle on 16B chunks: [m][k] -> m*128 + ((k>>3)^(m&7))*8 + (k&7).
__global__ void convert_weights(const float* __restrict__ W1,
                                const float* __restrict__ W2,
                                const float* __restrict__ Wlin,
                                __bf16* __restrict__ dst) {
    int idx = blockIdx.x * blockDim.x + threadIdx.x;
    if (idx >= NSTAGE * HDIM * HDIM) return;
    int s    = idx >> 14;
    int rem  = idx & 16383;
    int mrow = rem >> 7;
    int k    = rem & 127;
    const float* src;
    if (s == 6) src = Wlin;
    else {
        int l = s >> 1;
        src = ((s & 1) ? W2 : W1) + l * HDIM * HDIM;
    }
    float v = src[mrow * HDIM + k];
    int dsti = (s << 14) + (mrow << 7) + ((((k >> 3) ^ (mrow & 7)) << 3) | (k & 7));
    dst[dsti] = (__bf16)v;
}

// ---- atomic-free counting sort of edges by target node ----
// Phase A: per-block (8192-edge chunk) LDS histogram + per-edge rank within
// (block,node). Only LDS atomics (avg <1 op/bin/block) — no global atomics.
__global__ __launch_bounds__(1024) void hist_rank_kernel(
    const int* __restrict__ tgt,
    unsigned short* __restrict__ rank,
    int* __restrict__ hb,
    int E, int N)
{
    __shared__ int lh[10240];   // N = 10000 for this problem
    for (int i = threadIdx.x; i < N; i += 1024) lh[i] = 0;
    __syncthreads();
    int ebase = blockIdx.x << CHUNK_LOG;
    int eend  = min(ebase + CHUNK, E);
    for (int e = ebase + (int)threadIdx.x; e < eend; e += 1024) {
        int node = tgt[e];
        int r = atomicAdd(&lh[node], 1);   // LDS atomic — fast
        rank[e] = (unsigned short)r;       // coalesced
    }
    __syncthreads();
    int* row = hb + (size_t)blockIdx.x * N;
    for (int i = threadIdx.x; i < N; i += 1024) row[i] = lh[i];  // coalesced
}

// Phase B1: tot[n] = sum over blocks of hb[b][n]  (coalesced along n)
__global__ void colsum_kernel(const int* __restrict__ hb, int* __restrict__ tot,
                              int nblk, int N) {
    int n = blockIdx.x * blockDim.x + threadIdx.x;
    if (n >= N) return;
    int s = 0;
    for (int b = 0; b < nblk; ++b) s += hb[(size_t)b * N + n];
    tot[n] = s;
}

// Phase B2: exclusive scan over nodes (reused from previous version)
__global__ __launch_bounds__(1024) void scan_kernel(const int* __restrict__ hist,
                                                    int* __restrict__ cursor, int N) {
    __shared__ int part[1024];
    int t = threadIdx.x;
    int per = (N + 1023) >> 10;
    int lo = t * per, hi = min(lo + per, N);
    int s = 0;
    for (int i = lo; i < hi; ++i) s += hist[i];
    part[t] = s;
    __syncthreads();
    for (int d = 1; d < 1024; d <<= 1) {
        int v = (t >= d) ? part[t - d] : 0;
        __syncthreads();
        part[t] += v;
        __syncthreads();
    }
    int off = (t == 0) ? 0 : part[t - 1];
    for (int i = lo; i < hi; ++i) { cursor[i] = off; off += hist[i]; }
}

// Phase B3: in-place transform hb[b][n] -> global base offset for (block,node)
__global__ void offsets_kernel(int* __restrict__ hb, const int* __restrict__ base,
                               int nblk, int N) {
    int n = blockIdx.x * blockDim.x + threadIdx.x;
    if (n >= N) return;
    int run = base[n];
    for (int b = 0; b < nblk; ++b) {
        size_t idx = (size_t)b * N + n;
        int c = hb[idx];
        hb[idx] = run;
        run += c;
    }
}

// Phase C: emit sorted permutation. Zero atomics; pos unique by construction.
__global__ void emit_perm_kernel(const int* __restrict__ tgt,
                                 const unsigned short* __restrict__ rank,
                                 const int* __restrict__ hb,
                                 int* __restrict__ perm, int* __restrict__ snode,
                                 int E, int N) {
    int e = blockIdx.x * blockDim.x + threadIdx.x;
    if (e >= E) return;
    int node = tgt[e];
    int b = e >> CHUNK_LOG;
    int pos = hb[(size_t)b * N + node] + (int)rank[e];
    perm[pos] = e;
    snode[pos] = node;
}

// One wave owns 32 sorted-order edges end-to-end; residual X in fp32 regs.
// Matmuls transposed: D[feat][edge] via mfma_f32_32x32x16_bf16.
// C/D: edge=lane&31, feat=mb*32+(reg&3)+8*(reg>>2)+4*(lane>>5).
// Activation LDS: per edge-row stride 136 bf16, 16B-granule rotation swizzle.
// W staging is SOFTWARE-PIPELINED through registers: stage s+1's 32 KB tile
// is global-loaded into 8 bf16x8 regs/thread during stage s's compute; the
// vmcnt drain lands a full compute-phase after issue instead of right before
// the barrier (removes per-stage L2-latency exposure on the critical path).
__global__ __launch_bounds__(256, 2) void fused_mlp_scatter(
    const float* __restrict__ m,
    const int* __restrict__ perm,
    const int* __restrict__ snode,
    const __bf16* __restrict__ wmats,
    const float* __restrict__ b1,
    const float* __restrict__ b2,
    const float* __restrict__ blin,
    float* __restrict__ out,
    int E, int ntiles)
{
    __shared__ __align__(16) char smem[67584];
    __bf16* wlds   = (__bf16*)smem;                  // 32 KB
    __bf16* actAll = (__bf16*)(smem + 32768);        // 4*32*136 bf16
    float*  ybuf   = (float*)smem;                   // 4*32*132 f32 (overlay)

    const int tid  = threadIdx.x;
    const int w    = tid >> 6;
    const int lane = tid & 63;
    const int l31  = lane & 31;
    const int half = lane >> 5;

    const int tile    = blockIdx.x * 4 + w;
    const bool activeW = (tile < ntiles);
    const int pos = tile * 32 + l31;
    const bool evalid = activeW && (pos < E);

    int eidx = 0, mynode = 0;
    if (evalid) { eidx = perm[pos]; mynode = snode[pos]; }

    floatx4 X[4][4];
    floatx16 acc[4];
    bf16x8 wpre[8];
    __bf16* actw = actAll + (w * 32 + l31) * 136;

    #define ACT_OFF(f) (((((((f) >> 4) + l31) & 7)) << 4) | ((f) & 15))

    // prefetch stage-0 W tile into registers (all 256 threads)
    #pragma unroll
    for (int i = 0; i < 8; ++i)
        wpre[i] = *(const bf16x8*)(wmats + i * 2048 + tid * 8);

    if (activeW) {
        const float* mrow = m + (size_t)eidx * HDIM;
        #pragma unroll
        for (int mb = 0; mb < 4; ++mb)
            #pragma unroll
            for (int q = 0; q < 4; ++q) {
                int f0 = mb * 32 + q * 8 + half * 4;
                X[mb][q] = *(const floatx4*)(mrow + f0);
            }
        #pragma unroll
        for (int mb = 0; mb < 4; ++mb)
            #pragma unroll
            for (int q = 0; q < 4; ++q) {
                int f0 = mb * 32 + q * 8 + half * 4;
                bf16x4 v;
                for (int j = 0; j < 4; ++j) v[j] = (__bf16)silu_f(X[mb][q][j]);
                *(bf16x4*)(actw + ACT_OFF(f0)) = v;
            }
    }

    #pragma unroll
    for (int s = 0; s < NSTAGE; ++s) {
        __syncthreads();   // all waves done reading wlds from previous stage
        #pragma unroll
        for (int i = 0; i < 8; ++i)
            *(bf16x8*)(&wlds[i * 2048 + tid * 8]) = wpre[i];
        __syncthreads();
        // issue next stage's W loads now; vmcnt drains during compute below
        if (s < NSTAGE - 1) {
            const __bf16* wsrc = wmats + ((s + 1) << 14);
            #pragma unroll
            for (int i = 0; i < 8; ++i)
                wpre[i] = *(const bf16x8*)(wsrc + i * 2048 + tid * 8);
        }
        if (!activeW) continue;

        #pragma unroll
        for (int mb = 0; mb < 4; ++mb)
            for (int r = 0; r < 16; ++r) acc[mb][r] = 0.0f;

        #pragma unroll
        for (int ks = 0; ks < 8; ++ks) {
            bf16x8 bfrag = *(const bf16x8*)(actw + ((((ks + l31) & 7) << 4) + half * 8));
            int krow = ks * 2 + half;
            #pragma unroll
            for (int mb = 0; mb < 4; ++mb) {
                int mr = mb * 32 + l31;
                bf16x8 afrag = *(const bf16x8*)(&wlds[(mr << 7) + ((krow ^ (mr & 7)) << 3)]);
                acc[mb] = __builtin_amdgcn_mfma_f32_32x32x16_bf16(afrag, bfrag, acc[mb], 0, 0, 0);
            }
        }

        if (s == 6) {
            // blin + silu IN-PLACE into acc (carried across the barrier below)
            #pragma unroll
            for (int mb = 0; mb < 4; ++mb)
                #pragma unroll
                for (int q = 0; q < 4; ++q) {
                    int f0 = mb * 32 + q * 8 + half * 4;
                    floatx4 bv = *(const floatx4*)(blin + f0);
                    for (int j = 0; j < 4; ++j)
                        acc[mb][q * 4 + j] = silu_f(acc[mb][q * 4 + j] + bv[j]);
                }
        } else if ((s & 1) == 0) {
            const float* bias = b1 + (s >> 1) * HDIM;
            #pragma unroll
            for (int mb = 0; mb < 4; ++mb)
                #pragma unroll
                for (int q = 0; q < 4; ++q) {
                    int f0 = mb * 32 + q * 8 + half * 4;
                    floatx4 bv = *(const floatx4*)(bias + f0);
                    bf16x4 hv;
                    for (int j = 0; j < 4; ++j)
                        hv[j] = (__bf16)silu_f(acc[mb][q * 4 + j] + bv[j]);
                    *(bf16x4*)(actw + ACT_OFF(f0)) = hv;
                }
        } else {
            const float* bias = b2 + (s >> 1) * HDIM;
            #pragma unroll
            for (int mb = 0; mb < 4; ++mb)
                #pragma unroll
                for (int q = 0; q < 4; ++q) {
                    int f0 = mb * 32 + q * 8 + half * 4;
                    floatx4 bv = *(const floatx4*)(bias + f0);
                    bf16x4 xv;
                    for (int j = 0; j < 4; ++j) {
                        float nx = X[mb][q][j] + acc[mb][q * 4 + j] + bv[j];
                        X[mb][q][j] = nx;
                        xv[j] = (__bf16)((s == 5) ? nx : silu_f(nx));
                    }
                    *(bf16x4*)(actw + ACT_OFF(f0)) = xv;
                }
        }
    }

    // ---- epilogue: all waves must be done with wlds/actAll before overlay ----
    __syncthreads();
    if (activeW) {
        float* yrow = ybuf + (w * 32 + l31) * 132;
        #pragma unroll
        for (int mb = 0; mb < 4; ++mb)
            #pragma unroll
            for (int q = 0; q < 4; ++q) {
                int f0 = mb * 32 + q * 8 + half * 4;
                floatx4 v;
                for (int j = 0; j < 4; ++j) v[j] = acc[mb][q * 4 + j];
                *(floatx4*)(yrow + f0) = v;
            }
        // wave-private from here: segmented accumulate + atomic row-writes
        const float* yb = ybuf + w * 32 * 132;
        const int ebase = tile * 32;
        const int cnt = min(32, E - ebase);
        int cur = __builtin_amdgcn_readlane(mynode, 0);
        float a0 = 0.f, a1 = 0.f;
        for (int e = 0; e < cnt; ++e) {
            int node = __builtin_amdgcn_readlane(mynode, e);
            if (node != cur) {
                float* op = out + (size_t)cur * HDIM;
                unsafeAtomicAdd(op + lane, a0);
                unsafeAtomicAdd(op + 64 + lane, a1);
                cur = node; a0 = 0.f; a1 = 0.f;
            }
            a0 += yb[e * 132 + lane];
            a1 += yb[e * 132 + 64 + lane];
        }
        float* op = out + (size_t)cur * HDIM;
        unsafeAtomicAdd(op + lane, a0);
        unsafeAtomicAdd(op + 64 + lane, a1);
    }
    #undef ACT_OFF
}

extern "C" void kernel_launch(void* const* d_in, const int* in_sizes, int n_in,
                              void* d_out, int out_size, void* d_ws, size_t ws_size,
                              hipStream_t stream) {
    const float* m      = (const float*)d_in[0];
    const int* edge_idx = (const int*)d_in[1];
    const float* W1     = (const float*)d_in[3];
    const float* b1     = (const float*)d_in[4];
    const float* W2     = (const float*)d_in[5];
    const float* b2     = (const float*)d_in[6];
    const float* Wlin   = (const float*)d_in[7];
    const float* blin   = (const float*)d_in[8];

    int E = in_sizes[0] / HDIM;
    int N = out_size / HDIM;
    const int* tgt = edge_idx + E;

    int nblk = (E + CHUNK - 1) >> CHUNK_LOG;   // 8192-edge chunks (62 for E=500k)

    // workspace layout (256B-aligned)
    char* ws = (char*)d_ws;
    size_t off = 0;
    auto align_up = [](size_t v) { return (v + 255) & ~(size_t)255; };

    __bf16* wbf = (__bf16*)(ws + off);
    off = align_up(off + (size_t)NSTAGE * HDIM * HDIM * sizeof(__bf16));
    unsigned short* rank = (unsigned short*)(ws + off);
    off = align_up(off + (size_t)E * sizeof(unsigned short));
    int* hb = (int*)(ws + off);
    off = align_up(off + (size_t)nblk * N * sizeof(int));
    int* tot = (int*)(ws + off);
    off = align_up(off + (size_t)N * sizeof(int));
    int* base = (int*)(ws + off);
    off = align_up(off + (size_t)N * sizeof(int));
    int* perm = (int*)(ws + off);
    off = align_up(off + (size_t)E * sizeof(int));
    int* snode = (int*)(ws + off);
    off = align_up(off + (size_t)E * sizeof(int));

    hipMemsetAsync(d_out, 0, (size_t)out_size * sizeof(float), stream);

    convert_weights<<<(NSTAGE * HDIM * HDIM + 255) / 256, 256, 0, stream>>>(W1, W2, Wlin, wbf);

    // atomic-free counting sort
    hist_rank_kernel<<<nblk, 1024, 0, stream>>>(tgt, rank, hb, E, N);
    colsum_kernel<<<(N + 255) / 256, 256, 0, stream>>>(hb, tot, nblk, N);
    scan_kernel<<<1, 1024, 0, stream>>>(tot, base, N);
    offsets_kernel<<<(N + 255) / 256, 256, 0, stream>>>(hb, base, nblk, N);
    emit_perm_kernel<<<(E + 255) / 256, 256, 0, stream>>>(tgt, rank, hb, perm, snode, E, N);

    int ntiles  = (E + 31) / 32;
    int nblocks = (ntiles + 3) / 4;
    fused_mlp_scatter<<<nblocks, 256, 0, stream>>>(m, perm, snode, wbf, b1, b2, blin,
                                                   (float*)d_out, E, ntiles);
}